// Round 14
// baseline (232.594 us; speedup 1.0000x reference)
//
#include <hip/hip_runtime.h>
#include <hip/hip_bf16.h>
#include <stdint.h>

#define G_    1024
#define NPG   64
#define EPG   256
#define N_    (G_*NPG)     // 65536
#define E_    (G_*EPG)     // 262144
#define IN_CH 768
#define CH    128
#define KSEL  128
#define HID   512          // 4*CH

// ---- output layout (element offsets, all float32) ----
#define NCH  (N_*CH)       // 8388608
#define GK   (G_*KSEL)     // 131072
#define OFF0 0
#define OFF1 (OFF0 + NCH)
#define OFF2 (OFF1 + 2*GK)
#define OFF3 (OFF2 + GK)
#define OFF4 (OFF3 + GK)
#define OFF5 (OFF4 + N_)
#define OFF6 (OFF5 + NCH)
#define OFF7 (OFF6 + 2*GK)
#define OFF8 (OFF7 + GK)
#define OFF9 (OFF8 + GK)
#define OFF10 (OFF9 + N_)

typedef unsigned short u16;
typedef unsigned int   u32;
typedef __attribute__((ext_vector_type(8))) short bf16x8;
typedef __attribute__((ext_vector_type(4))) float f32x4;

__device__ __forceinline__ u16 f2bf(float x) {
    union { float f; u32 u; } v; v.f = x;
    u32 r = v.u + 0x7fffu + ((v.u >> 16) & 1u);   // RNE
    return (u16)(r >> 16);
}
__device__ __forceinline__ float bf2f(u32 h) {
    union { u32 u; float f; } v; v.u = h << 16; return v.f;
}
__device__ __forceinline__ u16 bfc(float x) {
    __hip_bfloat16 h = __float2bfloat16(x);
    return *reinterpret_cast<u16*>(&h);
}

__global__ void k_deg(const int* __restrict__ ei, const float* __restrict__ ea,
                      float* __restrict__ deg) {
    int e = blockIdx.x * 256 + threadIdx.x;
    if (e < E_) atomicAdd(&deg[ei[E_ + e]], ea[e]);
}

// fused dis+norm
__global__ void k_norm(const int* __restrict__ ei, const float* __restrict__ ea,
                       const float* __restrict__ deg, float* __restrict__ norm) {
    int e = blockIdx.x * 256 + threadIdx.x;
    if (e >= E_) return;
    float dr = deg[ei[e]], dc = deg[ei[E_ + e]];
    float fr = dr > 0.f ? 1.0f / sqrtf(dr) : 0.f;
    float fc = dc > 0.f ? 1.0f / sqrtf(dc) : 0.f;
    norm[e] = fr * ea[e] * fc;
}

// Build TRANSPOSED bf16 weights (row = output col, cols = K).
__global__ void k_concat(const float* __restrict__ W1, const float* __restrict__ V1,
                         const float* __restrict__ W2, const float* __restrict__ V2,
                         const float* __restrict__ mw1,
                         u16* __restrict__ WV1t, u16* __restrict__ WV2t,
                         u16* __restrict__ Mwt) {
    int i = blockIdx.x * 256 + threadIdx.x;
    if (i < 256 * IN_CH) {
        int c = i / IN_CH, r = i - c * IN_CH;
        WV1t[i] = f2bf(c < CH ? W1[r*CH + c] : V1[r*CH + (c - CH)]);
    }
    if (i < 256 * CH) {
        int c = i >> 7, r = i & 127;
        WV2t[i] = f2bf(c < CH ? W2[r*CH + c] : V2[r*CH + (c - CH)]);
    }
    if (i < 1024 * CH) {
        int c = i >> 7, r = i & 127;
        Mwt[i] = f2bf(c < HID ? mw1[r*HID + c] : mw1[(CH + r)*HID + (c - HID)]);
    }
}

// Layer-1 GEMM (round-7 version verbatim).
__global__ __launch_bounds__(256) void k_gemm1(const float* __restrict__ Ap,
        const u16* __restrict__ Bt, u16* __restrict__ Cp) {
    __shared__ float As[2][128 * 32];     // 2 x 16 KB
    const int t = threadIdx.x;
    const int lane = t & 63, w = t >> 6;
    const int wr = (w >> 1) << 6, wc = (w & 1) << 6;
    const size_t bm = (size_t)blockIdx.x * 128;
    const size_t bn = (size_t)blockIdx.y * 128;
    const int r16 = lane & 15, kq = lane >> 4;

    int cid[4], grow[4], gcol[4];
    #pragma unroll
    for (int i = 0; i < 4; ++i) {
        int c = i * 256 + t;
        cid[i] = c;
        int row = c >> 3, sl = c & 7;
        grow[i] = row;
        gcol[i] = (sl ^ (row & 7)) * 4;
    }

    f32x4 acc[4][4];
    #pragma unroll
    for (int m = 0; m < 4; ++m)
        #pragma unroll
        for (int n = 0; n < 4; ++n)
            acc[m][n] = (f32x4){0.f, 0.f, 0.f, 0.f};

    #define STAGE(buf, k0)                                                      \
        do {                                                                    \
            _Pragma("unroll")                                                   \
            for (int i = 0; i < 4; ++i) {                                       \
                const float* src = Ap + (bm + grow[i]) * (size_t)IN_CH + (k0) + gcol[i]; \
                __builtin_amdgcn_global_load_lds(                               \
                    (const __attribute__((address_space(1))) void*)src,         \
                    (__attribute__((address_space(3))) void*)&As[buf][cid[i] * 4], \
                    16, 0, 0);                                                  \
            }                                                                   \
        } while (0)

    #define LOADB(bv, k0)                                                       \
        do {                                                                    \
            _Pragma("unroll")                                                   \
            for (int n = 0; n < 4; ++n)                                         \
                bv[n] = *(const bf16x8*)(Bt + (bn + wc + n * 16 + r16) * (size_t)IN_CH + (k0) + kq * 8); \
        } while (0)

    STAGE(0, 0);
    bf16x8 bc[4];
    LOADB(bc, 0);
    __syncthreads();

    const int nk = IN_CH / 32;     // 24
    int buf = 0;
    for (int ki = 0; ki < nk; ++ki) {
        bf16x8 bnx[4];
        if (ki + 1 < nk) {
            STAGE(buf ^ 1, (ki + 1) * 32);
            LOADB(bnx, (ki + 1) * 32);
        }
        bf16x8 a[4];
        #pragma unroll
        for (int m = 0; m < 4; ++m) {
            int row = wr + m * 16 + r16;
            int xr = row & 7;
            const float* base = &As[buf][row * 32];
            float4 q0 = *(const float4*)(base + (((2 * kq)     ^ xr) * 4));
            float4 q1 = *(const float4*)(base + (((2 * kq + 1) ^ xr) * 4));
            union { bf16x8 v; u16 s[8]; } pk;
            pk.s[0] = bfc(q0.x); pk.s[1] = bfc(q0.y); pk.s[2] = bfc(q0.z); pk.s[3] = bfc(q0.w);
            pk.s[4] = bfc(q1.x); pk.s[5] = bfc(q1.y); pk.s[6] = bfc(q1.z); pk.s[7] = bfc(q1.w);
            a[m] = pk.v;
        }
        #pragma unroll
        for (int m = 0; m < 4; ++m)
            #pragma unroll
            for (int n = 0; n < 4; ++n)
                acc[m][n] = __builtin_amdgcn_mfma_f32_16x16x32_bf16(a[m], bc[n], acc[m][n], 0, 0, 0);
        if (ki + 1 < nk) {
            #pragma unroll
            for (int n = 0; n < 4; ++n) bc[n] = bnx[n];
        }
        __syncthreads();
        buf ^= 1;
    }
    #undef STAGE
    #undef LOADB

    #pragma unroll
    for (int m = 0; m < 4; ++m)
        #pragma unroll
        for (int j = 0; j < 4; ++j) {
            size_t row = bm + wr + m * 16 + kq * 4 + j;
            #pragma unroll
            for (int n = 0; n < 4; ++n) {
                size_t col = bn + wc + n * 16 + r16;
                Cp[row * 256 + col] = f2bf(acc[m][n][j]);
            }
        }
}

// ======================= fused per-graph mega-kernel =======================
// 70.9 KB LDS -> 2 blocks/CU. Region overlay (all transitions barriered):
//   R0 [0,16640)      A_s f32[64*65] (ph1-4) -> key[256]+idx[256] (ph7)
//   R1 [16640,34048)  x1s u16[64][136] (ph2-3) -> x2s u16[64][136] (ph4-5)
//   R2 [34048,68864)  Ms u16[64][136] (ph1-2) -> MVs u16[64][272] (ph3-4)
//                     -> PQc u16[64][260] (ph5-6, hid chunked by 128)
//   R3 [68864,70912)  mw2s f32[512] (ph1-6)
__global__ __launch_bounds__(512, 4) void k_graph(const u16* __restrict__ B1b,
        const u16* __restrict__ WV2t, const u16* __restrict__ Mwt,
        const int* __restrict__ ei, const float* __restrict__ norm,
        const float* __restrict__ b1, const float* __restrict__ b2,
        const float* __restrict__ mb1, const float* __restrict__ mw2,
        const float* __restrict__ mb2, const float* __restrict__ ea,
        float* __restrict__ out) {
    __shared__ char Lds[70912];
    float* A_s   = (float*)(Lds + 0);
    float* key   = (float*)(Lds + 0);
    int*   idx   = (int*)(Lds + 1024);
    u16*   x1s   = (u16*)(Lds + 16640);
    u16*   x2s   = (u16*)(Lds + 16640);
    u16*   Ms    = (u16*)(Lds + 34048);
    u16*   MVs   = (u16*)(Lds + 34048);
    u16*   PQc   = (u16*)(Lds + 34048);
    float* mw2s  = (float*)(Lds + 68864);

    const int g = blockIdx.x, t = threadIdx.x;
    const int lane = t & 63, w = t >> 6;          // 8 waves
    const int r16 = lane & 15, kq = lane >> 4;
    const size_t nbase = (size_t)g * 64;
    union bfr { bf16x8 v; u16 s[8]; };

    // ---- phase 1: stage mw2, zero A_s, stage Ms, scatter edges ----
    if (t < 128) *(float4*)&mw2s[t * 4] = *(const float4*)&mw2[t * 4];
    for (int i = t; i < 64 * 65; i += 512) A_s[i] = 0.f;
    for (int i = t; i < 64 * 32; i += 512) {
        int row = i >> 5, c4 = (i & 31) << 2;
        *(uint2*)&Ms[row * 136 + c4] = *(const uint2*)(B1b + (nbase + row) * 256 + c4);
    }
    int er = 0, ec = 0; float env = 0.f;
    if (t < 256) { int e = g * 256 + t; er = ei[e] & 63; ec = ei[E_ + e] & 63; env = norm[e]; }
    __syncthreads();
    if (t < 256) atomicAdd(&A_s[er * 65 + ec], env);
    __syncthreads();

    // ---- phase 2: agg1 -> x1s = bf16(relu(A^T m + v + b1)) ----
    {
        const int n0 = w * 16;
        f32x4 acc[4];
        #pragma unroll
        for (int mt = 0; mt < 4; ++mt) acc[mt] = (f32x4){0.f, 0.f, 0.f, 0.f};
        #pragma unroll
        for (int ks = 0; ks < 2; ++ks) {
            bfr a[4], b;
            #pragma unroll
            for (int mt = 0; mt < 4; ++mt)
                #pragma unroll
                for (int i = 0; i < 8; ++i)
                    a[mt].s[i] = f2bf(A_s[(ks*32 + kq*8 + i) * 65 + mt*16 + r16]);
            #pragma unroll
            for (int i = 0; i < 8; ++i)
                b.s[i] = Ms[(ks*32 + kq*8 + i) * 136 + n0 + r16];
            #pragma unroll
            for (int mt = 0; mt < 4; ++mt)
                acc[mt] = __builtin_amdgcn_mfma_f32_16x16x32_bf16(a[mt].v, b.v, acc[mt], 0, 0, 0);
        }
        const int ch = w * 16 + r16;
        __syncthreads();   // Ms dead; x1s region safe to write (distinct), keep order
        #pragma unroll
        for (int mt = 0; mt < 4; ++mt)
            #pragma unroll
            for (int j = 0; j < 4; ++j) {
                int c = mt * 16 + kq * 4 + j;
                float v = bf2f(B1b[(nbase + c) * 256 + 128 + ch]) + b1[ch];
                x1s[c * 136 + ch] = f2bf(fmaxf(acc[mt][j] + v, 0.f));
            }
    }
    __syncthreads();

    // ---- phase 3: layer-2 GEMM  MVs = x1 @ WV2t^T ----
    {
        const int wc2 = w * 32;
        f32x4 acc[4][2];
        #pragma unroll
        for (int mt = 0; mt < 4; ++mt)
            #pragma unroll
            for (int n = 0; n < 2; ++n) acc[mt][n] = (f32x4){0.f, 0.f, 0.f, 0.f};
        #pragma unroll
        for (int ks = 0; ks < 4; ++ks) {
            bf16x8 a[4], b[2];
            #pragma unroll
            for (int mt = 0; mt < 4; ++mt)
                a[mt] = *(const bf16x8*)&x1s[(mt*16 + r16) * 136 + ks*32 + kq*8];
            #pragma unroll
            for (int n = 0; n < 2; ++n)
                b[n] = *(const bf16x8*)(WV2t + (size_t)(wc2 + n*16 + r16) * 128 + ks*32 + kq*8);
            #pragma unroll
            for (int mt = 0; mt < 4; ++mt)
                #pragma unroll
                for (int n = 0; n < 2; ++n)
                    acc[mt][n] = __builtin_amdgcn_mfma_f32_16x16x32_bf16(a[mt], b[n], acc[mt][n], 0, 0, 0);
        }
        #pragma unroll
        for (int mt = 0; mt < 4; ++mt)
            #pragma unroll
            for (int j = 0; j < 4; ++j) {
                int row = mt * 16 + kq * 4 + j;
                #pragma unroll
                for (int n = 0; n < 2; ++n)
                    MVs[row * 272 + wc2 + n*16 + r16] = f2bf(acc[mt][n][j]);
            }
    }
    __syncthreads();

    // ---- phase 4: agg2 -> out0/out5 + x2s (overlays dead x1s) ----
    {
        const int n0 = w * 16;
        f32x4 acc[4];
        #pragma unroll
        for (int mt = 0; mt < 4; ++mt) acc[mt] = (f32x4){0.f, 0.f, 0.f, 0.f};
        #pragma unroll
        for (int ks = 0; ks < 2; ++ks) {
            bfr a[4], b;
            #pragma unroll
            for (int mt = 0; mt < 4; ++mt)
                #pragma unroll
                for (int i = 0; i < 8; ++i)
                    a[mt].s[i] = f2bf(A_s[(ks*32 + kq*8 + i) * 65 + mt*16 + r16]);
            #pragma unroll
            for (int i = 0; i < 8; ++i)
                b.s[i] = MVs[(ks*32 + kq*8 + i) * 272 + n0 + r16];
            #pragma unroll
            for (int mt = 0; mt < 4; ++mt)
                acc[mt] = __builtin_amdgcn_mfma_f32_16x16x32_bf16(a[mt].v, b.v, acc[mt], 0, 0, 0);
        }
        const int ch = w * 16 + r16;
        #pragma unroll
        for (int mt = 0; mt < 4; ++mt)
            #pragma unroll
            for (int j = 0; j < 4; ++j) {
                int c = mt * 16 + kq * 4 + j;
                float v = bf2f(MVs[c * 272 + 128 + ch]) + b2[ch];
                float r = fmaxf(acc[mt][j] + v, 0.f);
                size_t node = nbase + c;
                out[OFF0 + node * 128 + ch] = r;
                out[OFF5 + node * 128 + ch] = r;
                x2s[c * 136 + ch] = f2bf(r);
            }
    }
    __syncthreads();

    // ---- phases 5+6 interleaved: hid chunks of 128 ----
    const int le = lane & 31, jh = lane >> 5;
    const int eloc = w * 32 + le;
    const int e_g = g * 256 + eloc;
    const int er6 = ei[e_g] & 63, ec6 = ei[E_ + e_g] & 63;
    float esum = 0.f;
    #pragma unroll 1
    for (int h = 0; h < 4; ++h) {
        // GEMM chunk: 256 cols (P-chunk 0-127, Q-chunk 128-255)
        const int wc5 = w * 32;
        f32x4 acc[4][2];
        #pragma unroll
        for (int mt = 0; mt < 4; ++mt)
            #pragma unroll
            for (int n = 0; n < 2; ++n) acc[mt][n] = (f32x4){0.f, 0.f, 0.f, 0.f};
        #pragma unroll
        for (int ks = 0; ks < 4; ++ks) {
            bf16x8 a[4], b[2];
            #pragma unroll
            for (int mt = 0; mt < 4; ++mt)
                a[mt] = *(const bf16x8*)&x2s[(mt*16 + r16) * 136 + ks*32 + kq*8];
            #pragma unroll
            for (int n = 0; n < 2; ++n) {
                int colc = wc5 + n * 16 + r16;
                int mwrow = (colc < 128) ? (h * 128 + colc) : (512 + h * 128 + (colc - 128));
                b[n] = *(const bf16x8*)(Mwt + (size_t)mwrow * 128 + ks*32 + kq*8);
            }
            #pragma unroll
            for (int mt = 0; mt < 4; ++mt)
                #pragma unroll
                for (int n = 0; n < 2; ++n)
                    acc[mt][n] = __builtin_amdgcn_mfma_f32_16x16x32_bf16(a[mt], b[n], acc[mt][n], 0, 0, 0);
        }
        #pragma unroll
        for (int n = 0; n < 2; ++n) {
            int colc = wc5 + n * 16 + r16;
            float bias = (colc < 128) ? mb1[h * 128 + colc] : 0.f;
            #pragma unroll
            for (int mt = 0; mt < 4; ++mt)
                #pragma unroll
                for (int j = 0; j < 4; ++j) {
                    int row = mt * 16 + kq * 4 + j;
                    PQc[row * 260 + colc] = f2bf(acc[mt][n][j] + bias);
                }
        }
        __syncthreads();
        // edge partial over this chunk's 128 hiddens (jh splits into 2x64)
        {
            const u16* pP = &PQc[er6 * 260 + jh * 64];
            const u16* pQ = &PQc[ec6 * 260 + 128 + jh * 64];
            const float* pW = &mw2s[h * 128 + jh * 64];
            #pragma unroll
            for (int it = 0; it < 8; ++it) {
                uint4 up = *(const uint4*)(pP + it * 8);
                uint4 uq = *(const uint4*)(pQ + it * 8);
                float4 w0 = *(const float4*)(pW + it * 8);
                float4 w1 = *(const float4*)(pW + it * 8 + 4);
                u32 pu[4] = {up.x, up.y, up.z, up.w};
                u32 qu[4] = {uq.x, uq.y, uq.z, uq.w};
                float ww[8] = {w0.x,w0.y,w0.z,w0.w,w1.x,w1.y,w1.z,w1.w};
                #pragma unroll
                for (int k = 0; k < 4; ++k) {
                    float p0 = bf2f(pu[k] & 0xffffu), p1 = bf2f(pu[k] >> 16);
                    float q0 = bf2f(qu[k] & 0xffffu), q1 = bf2f(qu[k] >> 16);
                    esum += fmaxf(p0 + q0, 0.f) * ww[2*k];
                    esum += fmaxf(p1 + q1, 0.f) * ww[2*k + 1];
                }
            }
        }
        __syncthreads();
    }
    // finalize pred: combine jh halves; write key + OFF10
    {
        float s = esum + __shfl_xor(esum, 32, 64);
        if (lane < 32) {
            float pv = s + mb2[0];
            out[OFF10 + e_g] = pv;
            key[eloc] = pv;
            idx[eloc] = eloc;
        }
    }

    // ---- phase 7: stable bitonic top-K sort + remaining outputs ----
    for (int k2 = 2; k2 <= 256; k2 <<= 1) {
        for (int j = k2 >> 1; j >= 1; j >>= 1) {
            __syncthreads();
            if (t < 256) {
                int ixj = t ^ j;
                if (ixj > t) {
                    float ka = key[t], kb = key[ixj];
                    int   ia = idx[t], ib = idx[ixj];
                    bool up = ((t & k2) == 0);
                    bool a_before_b = (ka > kb) || (ka == kb && ia < ib);
                    bool do_swap = up ? !a_before_b : a_before_b;
                    if (do_swap) { key[t] = kb; key[ixj] = ka; idx[t] = ib; idx[ixj] = ia; }
                }
            }
        }
    }
    __syncthreads();
    if (t < 256) {
        int el = idx[t];
        int eg = g * 256 + el;
        float pv = key[t];
        float r = (float)ei[eg];
        float c = (float)ei[E_ + eg];
        float av = ea[eg];
        if (t < KSEL) {
            int oo = g * KSEL + t;
            out[OFF1 + oo]      = r;
            out[OFF1 + GK + oo] = c;
            out[OFF2 + oo]      = av;
            out[OFF3 + oo]      = pv;
        } else {
            int oo = g * KSEL + (t - KSEL);
            out[OFF6 + oo]      = r;
            out[OFF6 + GK + oo] = c;
            out[OFF7 + oo]      = av;
            out[OFF8 + oo]      = -pv;
        }
    }
    if (t < 64) {
        out[OFF4 + nbase + t] = (float)g;   // batch[node] == g
        out[OFF9 + nbase + t] = (float)g;
    }
}

extern "C" void kernel_launch(void* const* d_in, const int* in_sizes, int n_in,
                              void* d_out, int out_size, void* d_ws, size_t ws_size,
                              hipStream_t stream) {
    const float* x     = (const float*)d_in[0];
    const int*   ei    = (const int*)  d_in[1];
    const float* ea    = (const float*)d_in[2];
    const float* W1    = (const float*)d_in[4];
    const float* V1    = (const float*)d_in[5];
    const float* b1    = (const float*)d_in[6];
    const float* W2    = (const float*)d_in[7];
    const float* V2    = (const float*)d_in[8];
    const float* b2    = (const float*)d_in[9];
    const float* mw1   = (const float*)d_in[10];
    const float* mb1   = (const float*)d_in[11];
    const float* mw2   = (const float*)d_in[12];
    const float* mb2   = (const float*)d_in[13];
    float* out = (float*)d_out;

    char* ws = (char*)d_ws;
    size_t o = 0;
    float* deg  = (float*)(ws + o); o += (size_t)N_ * 4;          // 256 KB
    float* norm = (float*)(ws + o); o += (size_t)E_ * 4;          // 1 MB
    u16* WV1t   = (u16*)(ws + o);   o += (size_t)256 * IN_CH * 2; // 384 KB
    u16* WV2t   = (u16*)(ws + o);   o += (size_t)256 * CH * 2;    // 64 KB
    u16* Mwt    = (u16*)(ws + o);   o += (size_t)1024 * CH * 2;   // 256 KB
    u16* B1b    = (u16*)(ws + o);   o += (size_t)N_ * 256 * 2;    // 32 MB

    // prep
    hipMemsetAsync(deg, 0, (size_t)N_ * 4, stream);
    k_deg <<<E_/256, 256, 0, stream>>>(ei, ea, deg);
    k_norm<<<E_/256, 256, 0, stream>>>(ei, ea, deg, norm);
    k_concat<<<768, 256, 0, stream>>>(W1, V1, W2, V2, mw1, WV1t, WV2t, Mwt);

    // layer 1 GEMM
    dim3 g1(N_/128, 2);
    k_gemm1<<<g1, 256, 0, stream>>>(x, WV1t, B1b);

    // everything else fused per-graph
    k_graph<<<G_, 512, 0, stream>>>(B1b, WV2t, Mwt, ei, norm, b1, b2,
                                    mb1, mw2, mb2, ea, out);
}

// Round 15
// 215.329 us; speedup vs baseline: 1.0802x; 1.0802x over previous
//
#include <hip/hip_runtime.h>
#include <hip/hip_bf16.h>
#include <stdint.h>

#define G_    1024
#define NPG   64
#define EPG   256
#define N_    (G_*NPG)     // 65536
#define E_    (G_*EPG)     // 262144
#define IN_CH 768
#define CH    128
#define KSEL  128
#define HID   512          // 4*CH

// ---- output layout (element offsets, all float32) ----
#define NCH  (N_*CH)       // 8388608
#define GK   (G_*KSEL)     // 131072
#define OFF0 0
#define OFF1 (OFF0 + NCH)
#define OFF2 (OFF1 + 2*GK)
#define OFF3 (OFF2 + GK)
#define OFF4 (OFF3 + GK)
#define OFF5 (OFF4 + N_)
#define OFF6 (OFF5 + NCH)
#define OFF7 (OFF6 + 2*GK)
#define OFF8 (OFF7 + GK)
#define OFF9 (OFF8 + GK)
#define OFF10 (OFF9 + N_)

typedef unsigned short u16;
typedef unsigned int   u32;
typedef __attribute__((ext_vector_type(8))) short bf16x8;
typedef __attribute__((ext_vector_type(4))) float f32x4;

__device__ __forceinline__ u16 f2bf(float x) {
    union { float f; u32 u; } v; v.f = x;
    u32 r = v.u + 0x7fffu + ((v.u >> 16) & 1u);   // RNE
    return (u16)(r >> 16);
}
__device__ __forceinline__ float bf2f(u32 h) {
    union { u32 u; float f; } v; v.u = h << 16; return v.f;
}
__device__ __forceinline__ u16 bfc(float x) {
    __hip_bfloat16 h = __float2bfloat16(x);
    return *reinterpret_cast<u16*>(&h);
}

// Build TRANSPOSED bf16 weights (row = output col, cols = K).
__global__ void k_concat(const float* __restrict__ W1, const float* __restrict__ V1,
                         const float* __restrict__ W2, const float* __restrict__ V2,
                         const float* __restrict__ mw1,
                         u16* __restrict__ WV1t, u16* __restrict__ WV2t,
                         u16* __restrict__ Mwt) {
    int i = blockIdx.x * 256 + threadIdx.x;
    if (i < 256 * IN_CH) {
        int c = i / IN_CH, r = i - c * IN_CH;
        WV1t[i] = f2bf(c < CH ? W1[r*CH + c] : V1[r*CH + (c - CH)]);
    }
    if (i < 256 * CH) {
        int c = i >> 7, r = i & 127;
        WV2t[i] = f2bf(c < CH ? W2[r*CH + c] : V2[r*CH + (c - CH)]);
    }
    if (i < 1024 * CH) {
        int c = i >> 7, r = i & 127;
        Mwt[i] = f2bf(c < HID ? mw1[r*HID + c] : mw1[(CH + r)*HID + (c - HID)]);
    }
}

// Layer-1 GEMM (round-7 version verbatim, local floor 124 us across 7 variants).
__global__ __launch_bounds__(256) void k_gemm1(const float* __restrict__ Ap,
        const u16* __restrict__ Bt, u16* __restrict__ Cp) {
    __shared__ float As[2][128 * 32];     // 2 x 16 KB
    const int t = threadIdx.x;
    const int lane = t & 63, w = t >> 6;
    const int wr = (w >> 1) << 6, wc = (w & 1) << 6;
    const size_t bm = (size_t)blockIdx.x * 128;
    const size_t bn = (size_t)blockIdx.y * 128;
    const int r16 = lane & 15, kq = lane >> 4;

    int cid[4], grow[4], gcol[4];
    #pragma unroll
    for (int i = 0; i < 4; ++i) {
        int c = i * 256 + t;
        cid[i] = c;
        int row = c >> 3, sl = c & 7;
        grow[i] = row;
        gcol[i] = (sl ^ (row & 7)) * 4;
    }

    f32x4 acc[4][4];
    #pragma unroll
    for (int m = 0; m < 4; ++m)
        #pragma unroll
        for (int n = 0; n < 4; ++n)
            acc[m][n] = (f32x4){0.f, 0.f, 0.f, 0.f};

    #define STAGE(buf, k0)                                                      \
        do {                                                                    \
            _Pragma("unroll")                                                   \
            for (int i = 0; i < 4; ++i) {                                       \
                const float* src = Ap + (bm + grow[i]) * (size_t)IN_CH + (k0) + gcol[i]; \
                __builtin_amdgcn_global_load_lds(                               \
                    (const __attribute__((address_space(1))) void*)src,         \
                    (__attribute__((address_space(3))) void*)&As[buf][cid[i] * 4], \
                    16, 0, 0);                                                  \
            }                                                                   \
        } while (0)

    #define LOADB(bv, k0)                                                       \
        do {                                                                    \
            _Pragma("unroll")                                                   \
            for (int n = 0; n < 4; ++n)                                         \
                bv[n] = *(const bf16x8*)(Bt + (bn + wc + n * 16 + r16) * (size_t)IN_CH + (k0) + kq * 8); \
        } while (0)

    STAGE(0, 0);
    bf16x8 bc[4];
    LOADB(bc, 0);
    __syncthreads();

    const int nk = IN_CH / 32;     // 24
    int buf = 0;
    for (int ki = 0; ki < nk; ++ki) {
        bf16x8 bnx[4];
        if (ki + 1 < nk) {
            STAGE(buf ^ 1, (ki + 1) * 32);
            LOADB(bnx, (ki + 1) * 32);
        }
        bf16x8 a[4];
        #pragma unroll
        for (int m = 0; m < 4; ++m) {
            int row = wr + m * 16 + r16;
            int xr = row & 7;
            const float* base = &As[buf][row * 32];
            float4 q0 = *(const float4*)(base + (((2 * kq)     ^ xr) * 4));
            float4 q1 = *(const float4*)(base + (((2 * kq + 1) ^ xr) * 4));
            union { bf16x8 v; u16 s[8]; } pk;
            pk.s[0] = bfc(q0.x); pk.s[1] = bfc(q0.y); pk.s[2] = bfc(q0.z); pk.s[3] = bfc(q0.w);
            pk.s[4] = bfc(q1.x); pk.s[5] = bfc(q1.y); pk.s[6] = bfc(q1.z); pk.s[7] = bfc(q1.w);
            a[m] = pk.v;
        }
        #pragma unroll
        for (int m = 0; m < 4; ++m)
            #pragma unroll
            for (int n = 0; n < 4; ++n)
                acc[m][n] = __builtin_amdgcn_mfma_f32_16x16x32_bf16(a[m], bc[n], acc[m][n], 0, 0, 0);
        if (ki + 1 < nk) {
            #pragma unroll
            for (int n = 0; n < 4; ++n) bc[n] = bnx[n];
        }
        __syncthreads();
        buf ^= 1;
    }
    #undef STAGE
    #undef LOADB

    #pragma unroll
    for (int m = 0; m < 4; ++m)
        #pragma unroll
        for (int j = 0; j < 4; ++j) {
            size_t row = bm + wr + m * 16 + kq * 4 + j;
            #pragma unroll
            for (int n = 0; n < 4; ++n) {
                size_t col = bn + wc + n * 16 + r16;
                Cp[row * 256 + col] = f2bf(acc[m][n][j]);
            }
        }
}

// ======================= fused per-graph mega-kernel =======================
// Now also computes deg/norm in-block (edges are graph-local) and uses a
// barrier-free rank-scatter instead of bitonic sort (36 barriers -> 1).
// LDS overlay:
//   R0 [0,16640)      A_s f32[64*65] (ph1-4) -> key f32[256] (ph6-7)
//   R1 [16640,34048)  x1s u16[64][136] (ph2-3) -> x2s (ph4-5)
//   R2 [34048,68864)  Ms u16[64][136] (ph1-2) -> MVs u16[64][272] (ph3-4)
//                     -> PQc u16[64][260] (ph5-6, hid chunked by 128)
//   R3 [68864,70912)  mw2s f32[512]
//   R4 [70912,71168)  deg_s f32[64]
__global__ __launch_bounds__(512, 4) void k_graph(const u16* __restrict__ B1b,
        const u16* __restrict__ WV2t, const u16* __restrict__ Mwt,
        const int* __restrict__ ei,
        const float* __restrict__ b1, const float* __restrict__ b2,
        const float* __restrict__ mb1, const float* __restrict__ mw2,
        const float* __restrict__ mb2, const float* __restrict__ ea,
        float* __restrict__ out) {
    __shared__ char Lds[71168];
    float* A_s   = (float*)(Lds + 0);
    float* key   = (float*)(Lds + 0);
    u16*   x1s   = (u16*)(Lds + 16640);
    u16*   x2s   = (u16*)(Lds + 16640);
    u16*   Ms    = (u16*)(Lds + 34048);
    u16*   MVs   = (u16*)(Lds + 34048);
    u16*   PQc   = (u16*)(Lds + 34048);
    float* mw2s  = (float*)(Lds + 68864);
    float* deg_s = (float*)(Lds + 70912);

    const int g = blockIdx.x, t = threadIdx.x;
    const int lane = t & 63, w = t >> 6;          // 8 waves
    const int r16 = lane & 15, kq = lane >> 4;
    const size_t nbase = (size_t)g * 64;
    union bfr { bf16x8 v; u16 s[8]; };

    // ---- phase 1: stage mw2/Ms, zero A_s/deg_s, in-block deg->norm, edges ----
    if (t < 128) *(float4*)&mw2s[t * 4] = *(const float4*)&mw2[t * 4];
    for (int i = t; i < 64 * 65; i += 512) A_s[i] = 0.f;
    if (t < 64) deg_s[t] = 0.f;
    for (int i = t; i < 64 * 32; i += 512) {
        int row = i >> 5, c4 = (i & 31) << 2;
        *(uint2*)&Ms[row * 136 + c4] = *(const uint2*)(B1b + (nbase + row) * 256 + c4);
    }
    int rfull = 0, cfull = 0, er = 0, ec = 0; float eav = 0.f;
    if (t < 256) {
        int e = g * 256 + t;
        rfull = ei[e]; cfull = ei[E_ + e];
        er = rfull & 63; ec = cfull & 63;
        eav = ea[e];
    }
    __syncthreads();
    if (t < 256) atomicAdd(&deg_s[ec], eav);
    __syncthreads();
    if (t < 256) {
        float dr = deg_s[er], dc = deg_s[ec];
        float fr = dr > 0.f ? 1.0f / sqrtf(dr) : 0.f;
        float fc = dc > 0.f ? 1.0f / sqrtf(dc) : 0.f;
        atomicAdd(&A_s[er * 65 + ec], fr * eav * fc);
    }
    __syncthreads();

    // ---- phase 2: agg1 -> x1s = bf16(relu(A^T m + v + b1)) ----
    {
        const int n0 = w * 16;
        f32x4 acc[4];
        #pragma unroll
        for (int mt = 0; mt < 4; ++mt) acc[mt] = (f32x4){0.f, 0.f, 0.f, 0.f};
        #pragma unroll
        for (int ks = 0; ks < 2; ++ks) {
            bfr a[4], b;
            #pragma unroll
            for (int mt = 0; mt < 4; ++mt)
                #pragma unroll
                for (int i = 0; i < 8; ++i)
                    a[mt].s[i] = f2bf(A_s[(ks*32 + kq*8 + i) * 65 + mt*16 + r16]);
            #pragma unroll
            for (int i = 0; i < 8; ++i)
                b.s[i] = Ms[(ks*32 + kq*8 + i) * 136 + n0 + r16];
            #pragma unroll
            for (int mt = 0; mt < 4; ++mt)
                acc[mt] = __builtin_amdgcn_mfma_f32_16x16x32_bf16(a[mt].v, b.v, acc[mt], 0, 0, 0);
        }
        const int ch = w * 16 + r16;
        __syncthreads();   // Ms dead before x1 consumers start
        #pragma unroll
        for (int mt = 0; mt < 4; ++mt)
            #pragma unroll
            for (int j = 0; j < 4; ++j) {
                int c = mt * 16 + kq * 4 + j;
                float v = bf2f(B1b[(nbase + c) * 256 + 128 + ch]) + b1[ch];
                x1s[c * 136 + ch] = f2bf(fmaxf(acc[mt][j] + v, 0.f));
            }
    }
    __syncthreads();

    // ---- phase 3: layer-2 GEMM  MVs = x1 @ WV2t^T ----
    {
        const int wc2 = w * 32;
        f32x4 acc[4][2];
        #pragma unroll
        for (int mt = 0; mt < 4; ++mt)
            #pragma unroll
            for (int n = 0; n < 2; ++n) acc[mt][n] = (f32x4){0.f, 0.f, 0.f, 0.f};
        #pragma unroll
        for (int ks = 0; ks < 4; ++ks) {
            bf16x8 a[4], b[2];
            #pragma unroll
            for (int mt = 0; mt < 4; ++mt)
                a[mt] = *(const bf16x8*)&x1s[(mt*16 + r16) * 136 + ks*32 + kq*8];
            #pragma unroll
            for (int n = 0; n < 2; ++n)
                b[n] = *(const bf16x8*)(WV2t + (size_t)(wc2 + n*16 + r16) * 128 + ks*32 + kq*8);
            #pragma unroll
            for (int mt = 0; mt < 4; ++mt)
                #pragma unroll
                for (int n = 0; n < 2; ++n)
                    acc[mt][n] = __builtin_amdgcn_mfma_f32_16x16x32_bf16(a[mt], b[n], acc[mt][n], 0, 0, 0);
        }
        #pragma unroll
        for (int mt = 0; mt < 4; ++mt)
            #pragma unroll
            for (int j = 0; j < 4; ++j) {
                int row = mt * 16 + kq * 4 + j;
                #pragma unroll
                for (int n = 0; n < 2; ++n)
                    MVs[row * 272 + wc2 + n*16 + r16] = f2bf(acc[mt][n][j]);
            }
    }
    __syncthreads();

    // ---- phase 4: agg2 -> out0/out5 + x2s ----
    {
        const int n0 = w * 16;
        f32x4 acc[4];
        #pragma unroll
        for (int mt = 0; mt < 4; ++mt) acc[mt] = (f32x4){0.f, 0.f, 0.f, 0.f};
        #pragma unroll
        for (int ks = 0; ks < 2; ++ks) {
            bfr a[4], b;
            #pragma unroll
            for (int mt = 0; mt < 4; ++mt)
                #pragma unroll
                for (int i = 0; i < 8; ++i)
                    a[mt].s[i] = f2bf(A_s[(ks*32 + kq*8 + i) * 65 + mt*16 + r16]);
            #pragma unroll
            for (int i = 0; i < 8; ++i)
                b.s[i] = MVs[(ks*32 + kq*8 + i) * 272 + n0 + r16];
            #pragma unroll
            for (int mt = 0; mt < 4; ++mt)
                acc[mt] = __builtin_amdgcn_mfma_f32_16x16x32_bf16(a[mt].v, b.v, acc[mt], 0, 0, 0);
        }
        const int ch = w * 16 + r16;
        #pragma unroll
        for (int mt = 0; mt < 4; ++mt)
            #pragma unroll
            for (int j = 0; j < 4; ++j) {
                int c = mt * 16 + kq * 4 + j;
                float v = bf2f(MVs[c * 272 + 128 + ch]) + b2[ch];
                float r = fmaxf(acc[mt][j] + v, 0.f);
                size_t node = nbase + c;
                out[OFF0 + node * 128 + ch] = r;
                out[OFF5 + node * 128 + ch] = r;
                x2s[c * 136 + ch] = f2bf(r);
            }
    }
    __syncthreads();

    // ---- phases 5+6 interleaved: hid chunks of 128 ----
    const int le = lane & 31, jh = lane >> 5;
    const int eloc = w * 32 + le;
    const int e_g = g * 256 + eloc;
    const int er6 = ei[e_g] & 63, ec6 = ei[E_ + e_g] & 63;
    float esum = 0.f;
    #pragma unroll 1
    for (int h = 0; h < 4; ++h) {
        const int wc5 = w * 32;
        f32x4 acc[4][2];
        #pragma unroll
        for (int mt = 0; mt < 4; ++mt)
            #pragma unroll
            for (int n = 0; n < 2; ++n) acc[mt][n] = (f32x4){0.f, 0.f, 0.f, 0.f};
        #pragma unroll
        for (int ks = 0; ks < 4; ++ks) {
            bf16x8 a[4], b[2];
            #pragma unroll
            for (int mt = 0; mt < 4; ++mt)
                a[mt] = *(const bf16x8*)&x2s[(mt*16 + r16) * 136 + ks*32 + kq*8];
            #pragma unroll
            for (int n = 0; n < 2; ++n) {
                int colc = wc5 + n * 16 + r16;
                int mwrow = (colc < 128) ? (h * 128 + colc) : (512 + h * 128 + (colc - 128));
                b[n] = *(const bf16x8*)(Mwt + (size_t)mwrow * 128 + ks*32 + kq*8);
            }
            #pragma unroll
            for (int mt = 0; mt < 4; ++mt)
                #pragma unroll
                for (int n = 0; n < 2; ++n)
                    acc[mt][n] = __builtin_amdgcn_mfma_f32_16x16x32_bf16(a[mt], b[n], acc[mt][n], 0, 0, 0);
        }
        #pragma unroll
        for (int n = 0; n < 2; ++n) {
            int colc = wc5 + n * 16 + r16;
            float bias = (colc < 128) ? mb1[h * 128 + colc] : 0.f;
            #pragma unroll
            for (int mt = 0; mt < 4; ++mt)
                #pragma unroll
                for (int j = 0; j < 4; ++j) {
                    int row = mt * 16 + kq * 4 + j;
                    PQc[row * 260 + colc] = f2bf(acc[mt][n][j] + bias);
                }
        }
        __syncthreads();
        {
            const u16* pP = &PQc[er6 * 260 + jh * 64];
            const u16* pQ = &PQc[ec6 * 260 + 128 + jh * 64];
            const float* pW = &mw2s[h * 128 + jh * 64];
            #pragma unroll
            for (int it = 0; it < 8; ++it) {
                uint4 up = *(const uint4*)(pP + it * 8);
                uint4 uq = *(const uint4*)(pQ + it * 8);
                float4 w0 = *(const float4*)(pW + it * 8);
                float4 w1 = *(const float4*)(pW + it * 8 + 4);
                u32 pu[4] = {up.x, up.y, up.z, up.w};
                u32 qu[4] = {uq.x, uq.y, uq.z, uq.w};
                float ww[8] = {w0.x,w0.y,w0.z,w0.w,w1.x,w1.y,w1.z,w1.w};
                #pragma unroll
                for (int k = 0; k < 4; ++k) {
                    float p0 = bf2f(pu[k] & 0xffffu), p1 = bf2f(pu[k] >> 16);
                    float q0 = bf2f(qu[k] & 0xffffu), q1 = bf2f(qu[k] >> 16);
                    esum += fmaxf(p0 + q0, 0.f) * ww[2*k];
                    esum += fmaxf(p1 + q1, 0.f) * ww[2*k + 1];
                }
            }
        }
        __syncthreads();
    }
    // finalize pred: combine halves; write key (A_s region is dead) + OFF10
    {
        float s = esum + __shfl_xor(esum, 32, 64);
        if (lane < 32) {
            float pv = s + mb2[0];
            out[OFF10 + e_g] = pv;
            key[eloc] = pv;
        }
    }
    __syncthreads();

    // ---- phase 7: barrier-free stable rank-scatter (desc, ties by idx) ----
    if (t < 256) {
        float ki = key[t];
        int rank = 0;
        const float4* k4 = (const float4*)key;
        #pragma unroll 4
        for (int j4 = 0; j4 < 64; ++j4) {
            float4 kv = k4[j4];       // all lanes same address -> LDS broadcast
            int j = j4 * 4;
            rank += (kv.x > ki) || (kv.x == ki && (j + 0) < t);
            rank += (kv.y > ki) || (kv.y == ki && (j + 1) < t);
            rank += (kv.z > ki) || (kv.z == ki && (j + 2) < t);
            rank += (kv.w > ki) || (kv.w == ki && (j + 3) < t);
        }
        float r = (float)rfull;
        float c = (float)cfull;
        if (rank < KSEL) {
            int oo = g * KSEL + rank;
            out[OFF1 + oo]      = r;
            out[OFF1 + GK + oo] = c;
            out[OFF2 + oo]      = eav;
            out[OFF3 + oo]      = ki;
        } else {
            int oo = g * KSEL + (rank - KSEL);
            out[OFF6 + oo]      = r;
            out[OFF6 + GK + oo] = c;
            out[OFF7 + oo]      = eav;
            out[OFF8 + oo]      = -ki;
        }
    }
    if (t < 64) {
        out[OFF4 + nbase + t] = (float)g;   // batch[node] == g
        out[OFF9 + nbase + t] = (float)g;
    }
}

extern "C" void kernel_launch(void* const* d_in, const int* in_sizes, int n_in,
                              void* d_out, int out_size, void* d_ws, size_t ws_size,
                              hipStream_t stream) {
    const float* x     = (const float*)d_in[0];
    const int*   ei    = (const int*)  d_in[1];
    const float* ea    = (const float*)d_in[2];
    const float* W1    = (const float*)d_in[4];
    const float* V1    = (const float*)d_in[5];
    const float* b1    = (const float*)d_in[6];
    const float* W2    = (const float*)d_in[7];
    const float* V2    = (const float*)d_in[8];
    const float* b2    = (const float*)d_in[9];
    const float* mw1   = (const float*)d_in[10];
    const float* mb1   = (const float*)d_in[11];
    const float* mw2   = (const float*)d_in[12];
    const float* mb2   = (const float*)d_in[13];
    float* out = (float*)d_out;

    char* ws = (char*)d_ws;
    size_t o = 0;
    u16* WV1t   = (u16*)(ws + o);   o += (size_t)256 * IN_CH * 2; // 384 KB
    u16* WV2t   = (u16*)(ws + o);   o += (size_t)256 * CH * 2;    // 64 KB
    u16* Mwt    = (u16*)(ws + o);   o += (size_t)1024 * CH * 2;   // 256 KB
    u16* B1b    = (u16*)(ws + o);   o += (size_t)N_ * 256 * 2;    // 32 MB

    // prep: transposed bf16 weights only (deg/norm now in-block)
    k_concat<<<768, 256, 0, stream>>>(W1, V1, W2, V2, mw1, WV1t, WV2t, Mwt);

    // layer 1 GEMM
    dim3 g1(N_/128, 2);
    k_gemm1<<<g1, 256, 0, stream>>>(x, WV1t, B1b);

    // everything else fused per-graph
    k_graph<<<G_, 512, 0, stream>>>(B1b, WV2t, Mwt, ei, b1, b2,
                                    mb1, mw2, mb2, ea, out);
}

// Round 16
// 214.252 us; speedup vs baseline: 1.0856x; 1.0050x over previous
//
#include <hip/hip_runtime.h>
#include <hip/hip_bf16.h>
#include <stdint.h>

#define G_    1024
#define NPG   64
#define EPG   256
#define N_    (G_*NPG)     // 65536
#define E_    (G_*EPG)     // 262144
#define IN_CH 768
#define CH    128
#define KSEL  128
#define HID   512          // 4*CH

// ---- output layout (element offsets, all float32) ----
#define NCH  (N_*CH)       // 8388608
#define GK   (G_*KSEL)     // 131072
#define OFF0 0
#define OFF1 (OFF0 + NCH)
#define OFF2 (OFF1 + 2*GK)
#define OFF3 (OFF2 + GK)
#define OFF4 (OFF3 + GK)
#define OFF5 (OFF4 + N_)
#define OFF6 (OFF5 + NCH)
#define OFF7 (OFF6 + 2*GK)
#define OFF8 (OFF7 + GK)
#define OFF9 (OFF8 + GK)
#define OFF10 (OFF9 + N_)

typedef unsigned short u16;
typedef unsigned int   u32;
typedef __attribute__((ext_vector_type(8))) short bf16x8;
typedef __attribute__((ext_vector_type(4))) float f32x4;

__device__ __forceinline__ u16 f2bf(float x) {
    union { float f; u32 u; } v; v.f = x;
    u32 r = v.u + 0x7fffu + ((v.u >> 16) & 1u);   // RNE
    return (u16)(r >> 16);
}
__device__ __forceinline__ float bf2f(u32 h) {
    union { u32 u; float f; } v; v.u = h << 16; return v.f;
}
__device__ __forceinline__ u16 bfc(float x) {
    __hip_bfloat16 h = __float2bfloat16(x);
    return *reinterpret_cast<u16*>(&h);
}

// Build TRANSPOSED bf16 weights (row = output col, cols = K).
__global__ void k_concat(const float* __restrict__ W1, const float* __restrict__ V1,
                         const float* __restrict__ W2, const float* __restrict__ V2,
                         const float* __restrict__ mw1,
                         u16* __restrict__ WV1t, u16* __restrict__ WV2t,
                         u16* __restrict__ Mwt) {
    int i = blockIdx.x * 256 + threadIdx.x;
    if (i < 256 * IN_CH) {
        int c = i / IN_CH, r = i - c * IN_CH;
        WV1t[i] = f2bf(c < CH ? W1[r*CH + c] : V1[r*CH + (c - CH)]);
    }
    if (i < 256 * CH) {
        int c = i >> 7, r = i & 127;
        WV2t[i] = f2bf(c < CH ? W2[r*CH + c] : V2[r*CH + (c - CH)]);
    }
    if (i < 1024 * CH) {
        int c = i >> 7, r = i & 127;
        Mwt[i] = f2bf(c < HID ? mw1[r*HID + c] : mw1[(CH + r)*HID + (c - HID)]);
    }
}

// Layer-1 GEMM (round-7 version verbatim, local floor across 7 variants).
__global__ __launch_bounds__(256) void k_gemm1(const float* __restrict__ Ap,
        const u16* __restrict__ Bt, u16* __restrict__ Cp) {
    __shared__ float As[2][128 * 32];     // 2 x 16 KB
    const int t = threadIdx.x;
    const int lane = t & 63, w = t >> 6;
    const int wr = (w >> 1) << 6, wc = (w & 1) << 6;
    const size_t bm = (size_t)blockIdx.x * 128;
    const size_t bn = (size_t)blockIdx.y * 128;
    const int r16 = lane & 15, kq = lane >> 4;

    int cid[4], grow[4], gcol[4];
    #pragma unroll
    for (int i = 0; i < 4; ++i) {
        int c = i * 256 + t;
        cid[i] = c;
        int row = c >> 3, sl = c & 7;
        grow[i] = row;
        gcol[i] = (sl ^ (row & 7)) * 4;
    }

    f32x4 acc[4][4];
    #pragma unroll
    for (int m = 0; m < 4; ++m)
        #pragma unroll
        for (int n = 0; n < 4; ++n)
            acc[m][n] = (f32x4){0.f, 0.f, 0.f, 0.f};

    #define STAGE(buf, k0)                                                      \
        do {                                                                    \
            _Pragma("unroll")                                                   \
            for (int i = 0; i < 4; ++i) {                                       \
                const float* src = Ap + (bm + grow[i]) * (size_t)IN_CH + (k0) + gcol[i]; \
                __builtin_amdgcn_global_load_lds(                               \
                    (const __attribute__((address_space(1))) void*)src,         \
                    (__attribute__((address_space(3))) void*)&As[buf][cid[i] * 4], \
                    16, 0, 0);                                                  \
            }                                                                   \
        } while (0)

    #define LOADB(bv, k0)                                                       \
        do {                                                                    \
            _Pragma("unroll")                                                   \
            for (int n = 0; n < 4; ++n)                                         \
                bv[n] = *(const bf16x8*)(Bt + (bn + wc + n * 16 + r16) * (size_t)IN_CH + (k0) + kq * 8); \
        } while (0)

    STAGE(0, 0);
    bf16x8 bc[4];
    LOADB(bc, 0);
    __syncthreads();

    const int nk = IN_CH / 32;     // 24
    int buf = 0;
    for (int ki = 0; ki < nk; ++ki) {
        bf16x8 bnx[4];
        if (ki + 1 < nk) {
            STAGE(buf ^ 1, (ki + 1) * 32);
            LOADB(bnx, (ki + 1) * 32);
        }
        bf16x8 a[4];
        #pragma unroll
        for (int m = 0; m < 4; ++m) {
            int row = wr + m * 16 + r16;
            int xr = row & 7;
            const float* base = &As[buf][row * 32];
            float4 q0 = *(const float4*)(base + (((2 * kq)     ^ xr) * 4));
            float4 q1 = *(const float4*)(base + (((2 * kq + 1) ^ xr) * 4));
            union { bf16x8 v; u16 s[8]; } pk;
            pk.s[0] = bfc(q0.x); pk.s[1] = bfc(q0.y); pk.s[2] = bfc(q0.z); pk.s[3] = bfc(q0.w);
            pk.s[4] = bfc(q1.x); pk.s[5] = bfc(q1.y); pk.s[6] = bfc(q1.z); pk.s[7] = bfc(q1.w);
            a[m] = pk.v;
        }
        #pragma unroll
        for (int m = 0; m < 4; ++m)
            #pragma unroll
            for (int n = 0; n < 4; ++n)
                acc[m][n] = __builtin_amdgcn_mfma_f32_16x16x32_bf16(a[m], bc[n], acc[m][n], 0, 0, 0);
        if (ki + 1 < nk) {
            #pragma unroll
            for (int n = 0; n < 4; ++n) bc[n] = bnx[n];
        }
        __syncthreads();
        buf ^= 1;
    }
    #undef STAGE
    #undef LOADB

    #pragma unroll
    for (int m = 0; m < 4; ++m)
        #pragma unroll
        for (int j = 0; j < 4; ++j) {
            size_t row = bm + wr + m * 16 + kq * 4 + j;
            #pragma unroll
            for (int n = 0; n < 4; ++n) {
                size_t col = bn + wc + n * 16 + r16;
                Cp[row * 256 + col] = f2bf(acc[m][n][j]);
            }
        }
}

// ======================= fused per-graph mega-kernel =======================
// All global x2 writes moved OUT of the barrier-fenced phase chain into one
// fully-coalesced tail pass (1 KB/wave bursts, full 128B lines, no drain
// barrier after). Phase 4 writes only LDS.
// LDS overlay:
//   R0 [0,16640)      A_s f32[64*65] (ph1-4) -> key f32[256] (ph6-7)
//   R1 [16640,34048)  x1s u16[64][136] (ph2-3) -> x2s (ph4-end)
//   R2 [34048,68864)  Ms u16[64][136] (ph1-2) -> MVs u16[64][272] (ph3-4)
//                     -> PQc u16[64][260] (ph5-6, hid chunked by 128)
//   R3 [68864,70912)  mw2s f32[512]
//   R4 [70912,71168)  deg_s f32[64]
__global__ __launch_bounds__(512, 4) void k_graph(const u16* __restrict__ B1b,
        const u16* __restrict__ WV2t, const u16* __restrict__ Mwt,
        const int* __restrict__ ei,
        const float* __restrict__ b1, const float* __restrict__ b2,
        const float* __restrict__ mb1, const float* __restrict__ mw2,
        const float* __restrict__ mb2, const float* __restrict__ ea,
        float* __restrict__ out) {
    __shared__ char Lds[71168];
    float* A_s   = (float*)(Lds + 0);
    float* key   = (float*)(Lds + 0);
    u16*   x1s   = (u16*)(Lds + 16640);
    u16*   x2s   = (u16*)(Lds + 16640);
    u16*   Ms    = (u16*)(Lds + 34048);
    u16*   MVs   = (u16*)(Lds + 34048);
    u16*   PQc   = (u16*)(Lds + 34048);
    float* mw2s  = (float*)(Lds + 68864);
    float* deg_s = (float*)(Lds + 70912);

    const int g = blockIdx.x, t = threadIdx.x;
    const int lane = t & 63, w = t >> 6;          // 8 waves
    const int r16 = lane & 15, kq = lane >> 4;
    const size_t nbase = (size_t)g * 64;
    union bfr { bf16x8 v; u16 s[8]; };

    // ---- phase 1: stage mw2/Ms, zero A_s/deg_s, in-block deg->norm ----
    if (t < 128) *(float4*)&mw2s[t * 4] = *(const float4*)&mw2[t * 4];
    for (int i = t; i < 64 * 65; i += 512) A_s[i] = 0.f;
    if (t < 64) deg_s[t] = 0.f;
    for (int i = t; i < 64 * 32; i += 512) {
        int row = i >> 5, c4 = (i & 31) << 2;
        *(uint2*)&Ms[row * 136 + c4] = *(const uint2*)(B1b + (nbase + row) * 256 + c4);
    }
    int rfull = 0, cfull = 0, er = 0, ec = 0; float eav = 0.f;
    if (t < 256) {
        int e = g * 256 + t;
        rfull = ei[e]; cfull = ei[E_ + e];
        er = rfull & 63; ec = cfull & 63;
        eav = ea[e];
    }
    __syncthreads();
    if (t < 256) atomicAdd(&deg_s[ec], eav);
    __syncthreads();
    if (t < 256) {
        float dr = deg_s[er], dc = deg_s[ec];
        float fr = dr > 0.f ? 1.0f / sqrtf(dr) : 0.f;
        float fc = dc > 0.f ? 1.0f / sqrtf(dc) : 0.f;
        atomicAdd(&A_s[er * 65 + ec], fr * eav * fc);
    }
    __syncthreads();

    // ---- phase 2: agg1 -> x1s = bf16(relu(A^T m + v + b1)) ----
    {
        const int n0 = w * 16;
        f32x4 acc[4];
        #pragma unroll
        for (int mt = 0; mt < 4; ++mt) acc[mt] = (f32x4){0.f, 0.f, 0.f, 0.f};
        #pragma unroll
        for (int ks = 0; ks < 2; ++ks) {
            bfr a[4], b;
            #pragma unroll
            for (int mt = 0; mt < 4; ++mt)
                #pragma unroll
                for (int i = 0; i < 8; ++i)
                    a[mt].s[i] = f2bf(A_s[(ks*32 + kq*8 + i) * 65 + mt*16 + r16]);
            #pragma unroll
            for (int i = 0; i < 8; ++i)
                b.s[i] = Ms[(ks*32 + kq*8 + i) * 136 + n0 + r16];
            #pragma unroll
            for (int mt = 0; mt < 4; ++mt)
                acc[mt] = __builtin_amdgcn_mfma_f32_16x16x32_bf16(a[mt].v, b.v, acc[mt], 0, 0, 0);
        }
        const int ch = w * 16 + r16;
        __syncthreads();   // Ms dead before x1 consumers start
        #pragma unroll
        for (int mt = 0; mt < 4; ++mt)
            #pragma unroll
            for (int j = 0; j < 4; ++j) {
                int c = mt * 16 + kq * 4 + j;
                float v = bf2f(B1b[(nbase + c) * 256 + 128 + ch]) + b1[ch];
                x1s[c * 136 + ch] = f2bf(fmaxf(acc[mt][j] + v, 0.f));
            }
    }
    __syncthreads();

    // ---- phase 3: layer-2 GEMM  MVs = x1 @ WV2t^T ----
    {
        const int wc2 = w * 32;
        f32x4 acc[4][2];
        #pragma unroll
        for (int mt = 0; mt < 4; ++mt)
            #pragma unroll
            for (int n = 0; n < 2; ++n) acc[mt][n] = (f32x4){0.f, 0.f, 0.f, 0.f};
        #pragma unroll
        for (int ks = 0; ks < 4; ++ks) {
            bf16x8 a[4], b[2];
            #pragma unroll
            for (int mt = 0; mt < 4; ++mt)
                a[mt] = *(const bf16x8*)&x1s[(mt*16 + r16) * 136 + ks*32 + kq*8];
            #pragma unroll
            for (int n = 0; n < 2; ++n)
                b[n] = *(const bf16x8*)(WV2t + (size_t)(wc2 + n*16 + r16) * 128 + ks*32 + kq*8);
            #pragma unroll
            for (int mt = 0; mt < 4; ++mt)
                #pragma unroll
                for (int n = 0; n < 2; ++n)
                    acc[mt][n] = __builtin_amdgcn_mfma_f32_16x16x32_bf16(a[mt], b[n], acc[mt][n], 0, 0, 0);
        }
        #pragma unroll
        for (int mt = 0; mt < 4; ++mt)
            #pragma unroll
            for (int j = 0; j < 4; ++j) {
                int row = mt * 16 + kq * 4 + j;
                #pragma unroll
                for (int n = 0; n < 2; ++n)
                    MVs[row * 272 + wc2 + n*16 + r16] = f2bf(acc[mt][n][j]);
            }
    }
    __syncthreads();

    // ---- phase 4: agg2 -> x2s only (no global writes in phase chain) ----
    {
        const int n0 = w * 16;
        f32x4 acc[4];
        #pragma unroll
        for (int mt = 0; mt < 4; ++mt) acc[mt] = (f32x4){0.f, 0.f, 0.f, 0.f};
        #pragma unroll
        for (int ks = 0; ks < 2; ++ks) {
            bfr a[4], b;
            #pragma unroll
            for (int mt = 0; mt < 4; ++mt)
                #pragma unroll
                for (int i = 0; i < 8; ++i)
                    a[mt].s[i] = f2bf(A_s[(ks*32 + kq*8 + i) * 65 + mt*16 + r16]);
            #pragma unroll
            for (int i = 0; i < 8; ++i)
                b.s[i] = MVs[(ks*32 + kq*8 + i) * 272 + n0 + r16];
            #pragma unroll
            for (int mt = 0; mt < 4; ++mt)
                acc[mt] = __builtin_amdgcn_mfma_f32_16x16x32_bf16(a[mt].v, b.v, acc[mt], 0, 0, 0);
        }
        const int ch = w * 16 + r16;
        #pragma unroll
        for (int mt = 0; mt < 4; ++mt)
            #pragma unroll
            for (int j = 0; j < 4; ++j) {
                int c = mt * 16 + kq * 4 + j;
                float v = bf2f(MVs[c * 272 + 128 + ch]) + b2[ch];
                float r = fmaxf(acc[mt][j] + v, 0.f);
                x2s[c * 136 + ch] = f2bf(r);
            }
    }
    __syncthreads();

    // ---- phases 5+6 interleaved: hid chunks of 128 ----
    const int le = lane & 31, jh = lane >> 5;
    const int eloc = w * 32 + le;
    const int e_g = g * 256 + eloc;
    const int er6 = ei[e_g] & 63, ec6 = ei[E_ + e_g] & 63;
    float esum = 0.f;
    #pragma unroll 1
    for (int h = 0; h < 4; ++h) {
        const int wc5 = w * 32;
        f32x4 acc[4][2];
        #pragma unroll
        for (int mt = 0; mt < 4; ++mt)
            #pragma unroll
            for (int n = 0; n < 2; ++n) acc[mt][n] = (f32x4){0.f, 0.f, 0.f, 0.f};
        #pragma unroll
        for (int ks = 0; ks < 4; ++ks) {
            bf16x8 a[4], b[2];
            #pragma unroll
            for (int mt = 0; mt < 4; ++mt)
                a[mt] = *(const bf16x8*)&x2s[(mt*16 + r16) * 136 + ks*32 + kq*8];
            #pragma unroll
            for (int n = 0; n < 2; ++n) {
                int colc = wc5 + n * 16 + r16;
                int mwrow = (colc < 128) ? (h * 128 + colc) : (512 + h * 128 + (colc - 128));
                b[n] = *(const bf16x8*)(Mwt + (size_t)mwrow * 128 + ks*32 + kq*8);
            }
            #pragma unroll
            for (int mt = 0; mt < 4; ++mt)
                #pragma unroll
                for (int n = 0; n < 2; ++n)
                    acc[mt][n] = __builtin_amdgcn_mfma_f32_16x16x32_bf16(a[mt], b[n], acc[mt][n], 0, 0, 0);
        }
        #pragma unroll
        for (int n = 0; n < 2; ++n) {
            int colc = wc5 + n * 16 + r16;
            float bias = (colc < 128) ? mb1[h * 128 + colc] : 0.f;
            #pragma unroll
            for (int mt = 0; mt < 4; ++mt)
                #pragma unroll
                for (int j = 0; j < 4; ++j) {
                    int row = mt * 16 + kq * 4 + j;
                    PQc[row * 260 + colc] = f2bf(acc[mt][n][j] + bias);
                }
        }
        __syncthreads();
        {
            const u16* pP = &PQc[er6 * 260 + jh * 64];
            const u16* pQ = &PQc[ec6 * 260 + 128 + jh * 64];
            const float* pW = &mw2s[h * 128 + jh * 64];
            #pragma unroll
            for (int it = 0; it < 8; ++it) {
                uint4 up = *(const uint4*)(pP + it * 8);
                uint4 uq = *(const uint4*)(pQ + it * 8);
                float4 w0 = *(const float4*)(pW + it * 8);
                float4 w1 = *(const float4*)(pW + it * 8 + 4);
                u32 pu[4] = {up.x, up.y, up.z, up.w};
                u32 qu[4] = {uq.x, uq.y, uq.z, uq.w};
                float ww[8] = {w0.x,w0.y,w0.z,w0.w,w1.x,w1.y,w1.z,w1.w};
                #pragma unroll
                for (int k = 0; k < 4; ++k) {
                    float p0 = bf2f(pu[k] & 0xffffu), p1 = bf2f(pu[k] >> 16);
                    float q0 = bf2f(qu[k] & 0xffffu), q1 = bf2f(qu[k] >> 16);
                    esum += fmaxf(p0 + q0, 0.f) * ww[2*k];
                    esum += fmaxf(p1 + q1, 0.f) * ww[2*k + 1];
                }
            }
        }
        __syncthreads();
    }
    // finalize pred: combine halves; write key (A_s dead) + OFF10
    {
        float s = esum + __shfl_xor(esum, 32, 64);
        if (lane < 32) {
            float pv = s + mb2[0];
            out[OFF10 + e_g] = pv;
            key[eloc] = pv;
        }
    }
    __syncthreads();

    // ---- phase 7: barrier-free stable rank-scatter (desc, ties by idx) ----
    if (t < 256) {
        float ki = key[t];
        int rank = 0;
        const float4* k4 = (const float4*)key;
        #pragma unroll 4
        for (int j4 = 0; j4 < 64; ++j4) {
            float4 kv = k4[j4];       // all lanes same address -> LDS broadcast
            int j = j4 * 4;
            rank += (kv.x > ki) || (kv.x == ki && (j + 0) < t);
            rank += (kv.y > ki) || (kv.y == ki && (j + 1) < t);
            rank += (kv.z > ki) || (kv.z == ki && (j + 2) < t);
            rank += (kv.w > ki) || (kv.w == ki && (j + 3) < t);
        }
        float r = (float)rfull;
        float c = (float)cfull;
        if (rank < KSEL) {
            int oo = g * KSEL + rank;
            out[OFF1 + oo]      = r;
            out[OFF1 + GK + oo] = c;
            out[OFF2 + oo]      = eav;
            out[OFF3 + oo]      = ki;
        } else {
            int oo = g * KSEL + (rank - KSEL);
            out[OFF6 + oo]      = r;
            out[OFF6 + GK + oo] = c;
            out[OFF7 + oo]      = eav;
            out[OFF8 + oo]      = -ki;
        }
    }

    // ---- tail: fully-coalesced x2 -> out0/out5 + batch; no barrier after ----
    {
        float* o0 = out + OFF0 + nbase * 128;
        float* o5 = out + OFF5 + nbase * 128;
        #pragma unroll
        for (int it = 0; it < 4; ++it) {
            int i = it * 512 + t;             // float4 index, 2048 total
            int node = i >> 5;                // (i*4)>>7
            int ch4 = (i << 2) & 127;
            uint2 d = *(const uint2*)&x2s[node * 136 + ch4];
            float4 v;
            v.x = bf2f(d.x & 0xffffu); v.y = bf2f(d.x >> 16);
            v.z = bf2f(d.y & 0xffffu); v.w = bf2f(d.y >> 16);
            *(float4*)(o0 + (i << 2)) = v;
            *(float4*)(o5 + (i << 2)) = v;
        }
        if (t < 64) {
            out[OFF4 + nbase + t] = (float)g;
            out[OFF9 + nbase + t] = (float)g;
        }
    }
}

extern "C" void kernel_launch(void* const* d_in, const int* in_sizes, int n_in,
                              void* d_out, int out_size, void* d_ws, size_t ws_size,
                              hipStream_t stream) {
    const float* x     = (const float*)d_in[0];
    const int*   ei    = (const int*)  d_in[1];
    const float* ea    = (const float*)d_in[2];
    const float* W1    = (const float*)d_in[4];
    const float* V1    = (const float*)d_in[5];
    const float* b1    = (const float*)d_in[6];
    const float* W2    = (const float*)d_in[7];
    const float* V2    = (const float*)d_in[8];
    const float* b2    = (const float*)d_in[9];
    const float* mw1   = (const float*)d_in[10];
    const float* mb1   = (const float*)d_in[11];
    const float* mw2   = (const float*)d_in[12];
    const float* mb2   = (const float*)d_in[13];
    float* out = (float*)d_out;

    char* ws = (char*)d_ws;
    size_t o = 0;
    u16* WV1t   = (u16*)(ws + o);   o += (size_t)256 * IN_CH * 2; // 384 KB
    u16* WV2t   = (u16*)(ws + o);   o += (size_t)256 * CH * 2;    // 64 KB
    u16* Mwt    = (u16*)(ws + o);   o += (size_t)1024 * CH * 2;   // 256 KB
    u16* B1b    = (u16*)(ws + o);   o += (size_t)N_ * 256 * 2;    // 32 MB

    // prep: transposed bf16 weights (deg/norm in-block)
    k_concat<<<768, 256, 0, stream>>>(W1, V1, W2, V2, mw1, WV1t, WV2t, Mwt);

    // layer 1 GEMM
    dim3 g1(N_/128, 2);
    k_gemm1<<<g1, 256, 0, stream>>>(x, WV1t, B1b);

    // everything else fused per-graph
    k_graph<<<G_, 512, 0, stream>>>(B1b, WV2t, Mwt, ei, b1, b2,
                                    mb1, mw2, mb2, ea, out);
}